// Round 1
// baseline (1454.458 us; speedup 1.0000x reference)
//
#include <hip/hip_runtime.h>
#include <hip/hip_bf16.h>

#define NB   64     // batch
#define NS   128    // seq len
#define ND   256    // embed dim
#define NU   512    // hidden units
#define N3   1536   // 3*NU

typedef __attribute__((ext_vector_type(4))) float  f32x4;
typedef __attribute__((ext_vector_type(8))) short  s16x8;

__device__ __forceinline__ unsigned short f2bf(float v) {
  unsigned u = __builtin_bit_cast(unsigned, v);
  u += 0x7fffu + ((u >> 16) & 1u);          // round-to-nearest-even
  return (unsigned short)(u >> 16);
}

// -------- init: hx[0] = bf16(hidden); zero sync flags (graph-replay safe) --------
__global__ void init_kernel(const float* __restrict__ hidden,
                            unsigned short* __restrict__ hx,
                            unsigned int* __restrict__ flags) {
  const int b = blockIdx.x, u = threadIdx.x;   // 64 x 512
  hx[b * NU + u] = f2bf(hidden[b * NU + u]);
  if (b == 0) flags[u] = 0u;                   // 512 = 4 groups * 128 steps
}

// -------- phase 1: xp[m][n] = emb[x[m]][:] @ W[:,n] + b_in[n]  (f32 SIMT) --------
__global__ __launch_bounds__(256) void xproj_kernel(
    const int* __restrict__ x, const float* __restrict__ emb,
    const float* __restrict__ W, const float* __restrict__ bias,
    float* __restrict__ xp) {
  __shared__ float As[32][68];   // [k][m], padded
  __shared__ float Bs[32][68];   // [k][n], padded
  __shared__ int tok[64];
  const int tid = threadIdx.x;
  const int m0 = blockIdx.y * 64;
  const int n0 = blockIdx.x * 64;
  if (tid < 64) tok[tid] = x[m0 + tid];
  __syncthreads();
  const int tx = tid & 15, ty = tid >> 4;
  float acc[4][4] = {};
  for (int k0 = 0; k0 < ND; k0 += 32) {
    {  // stage A tile (gathered embedding rows), 64 rows x 32 k
      const int m = tid & 63, kq = tid >> 6;
      const float* src = emb + (size_t)tok[m] * ND + k0 + kq * 8;
      const float4 v0 = *(const float4*)(src);
      const float4 v1 = *(const float4*)(src + 4);
      As[kq*8+0][m] = v0.x; As[kq*8+1][m] = v0.y;
      As[kq*8+2][m] = v0.z; As[kq*8+3][m] = v0.w;
      As[kq*8+4][m] = v1.x; As[kq*8+5][m] = v1.y;
      As[kq*8+6][m] = v1.z; As[kq*8+7][m] = v1.w;
    }
    {  // stage B tile, 32 k x 64 n
      const int n = (tid & 15) * 4, k = tid >> 4;
      *(float4*)&Bs[k][n]    = *(const float4*)&W[(size_t)(k0 + k) * N3 + n0 + n];
      *(float4*)&Bs[k+16][n] = *(const float4*)&W[(size_t)(k0 + k + 16) * N3 + n0 + n];
    }
    __syncthreads();
    #pragma unroll
    for (int kk = 0; kk < 32; ++kk) {
      const float4 b4 = *(const float4*)&Bs[kk][tx * 4];
      float a[4];
      #pragma unroll
      for (int i = 0; i < 4; ++i) a[i] = As[kk][ty * 4 + i];
      #pragma unroll
      for (int i = 0; i < 4; ++i) {
        acc[i][0] += a[i] * b4.x;
        acc[i][1] += a[i] * b4.y;
        acc[i][2] += a[i] * b4.z;
        acc[i][3] += a[i] * b4.w;
      }
    }
    __syncthreads();
  }
  #pragma unroll
  for (int i = 0; i < 4; ++i) {
    const size_t row = (size_t)(m0 + ty * 4 + i) * N3 + n0 + tx * 4;
    float4 o;
    o.x = acc[i][0] + bias[n0 + tx*4 + 0];
    o.y = acc[i][1] + bias[n0 + tx*4 + 1];
    o.z = acc[i][2] + bias[n0 + tx*4 + 2];
    o.w = acc[i][3] + bias[n0 + tx*4 + 3];
    *(float4*)&xp[row] = o;
  }
}

// -------- phase 2: persistent GRU scan --------
// 256 blocks = 4 batch-groups (16 batches) x 64 unit-blocks (8 units -> 24 R cols).
// R slice lives in LDS (bf16, transposed) for all 128 steps. Per step: flag-sync,
// stage full h[t] (16x512 bf16), MFMA rp, f32 gates, write out + h[t+1], signal.
__global__ __launch_bounds__(128) void gru_scan_kernel(
    const float* __restrict__ xp, const float* __restrict__ hidden,
    const float* __restrict__ R, const float* __restrict__ bias,
    float* __restrict__ out, unsigned short* __restrict__ hx,
    unsigned int* __restrict__ flags) {
  __shared__ unsigned short Rt[32][520];  // [col][k] bf16, rows 24..31 zero pad
  __shared__ unsigned short hl[16][520];  // h[t] staged, padded rows
  __shared__ float rp[16][36];
  __shared__ float brec[24];

  const int bid = blockIdx.x;
  const int g   = bid >> 6;        // batch group 0..3
  const int u0  = (bid & 63) * 8;  // unit base
  const int tid = threadIdx.x;
  const int lane = tid & 63;
  const int wv   = tid >> 6;       // wave 0: cols 0-15 (z,r), wave 1: cols 16-23 (h)

  // one-time: stage R columns transposed to bf16 ([col][k], k contiguous)
  for (int idx = tid; idx < 24 * 512; idx += 128) {
    const int c = idx % 24;
    const int k = idx / 24;
    const int col = ((c >> 3) << 9) + u0 + (c & 7);   // gate*512 + unit
    Rt[c][k] = f2bf(R[(size_t)k * N3 + col]);
  }
  for (int idx = tid; idx < 8 * 512; idx += 128)
    Rt[24 + (idx >> 9)][idx & 511] = 0;
  if (tid < 24) brec[tid] = bias[N3 + ((tid >> 3) << 9) + u0 + (tid & 7)];

  const int ob = tid >> 3;          // batch within group 0..15
  const int ou = tid & 7;           // unit within block 0..7
  const int gb = (g << 4) + ob;     // global batch
  float hreg = hidden[(size_t)gb * NU + u0 + ou];  // f32 master copy of own h
  __syncthreads();

  const int ar = lane & 15;                 // A frag row (batch)
  const int kg = lane >> 4;                 // A/B frag k-group
  const int bc = (wv << 4) + ar;            // B frag col (Rt row)
  const int dcol = (wv << 4) + (lane & 15); // D col
  const int drow = (lane >> 4) << 2;        // D row base

  for (int t = 0; t < NS; ++t) {
    if (t > 0) {
      if (tid == 0) {
        while (__hip_atomic_load(&flags[(g << 7) + t - 1], __ATOMIC_ACQUIRE,
                                 __HIP_MEMORY_SCOPE_AGENT) < 64u) {
          __builtin_amdgcn_s_sleep(2);
        }
      }
      __syncthreads();
    }
    {  // stage h[t]: 16 rows x 512 bf16 = 16 KB
      const unsigned short* src = hx + ((size_t)t * NB + (g << 4)) * NU;
      for (int i = tid; i < 1024; i += 128) {
        const int r = i >> 6, cc = i & 63;
        *(s16x8*)&hl[r][cc * 8] = *(const s16x8*)&src[r * NU + cc * 8];
      }
    }
    __syncthreads();

    // rp = h[16x512] @ Rslice[512x(16 or 8+pad)] via 16 chained MFMAs
    f32x4 acc = {0.f, 0.f, 0.f, 0.f};
    #pragma unroll
    for (int ks = 0; ks < 16; ++ks) {
      const int kb = ks * 32 + kg * 8;
      const s16x8 af = *(const s16x8*)&hl[ar][kb];
      const s16x8 bf = *(const s16x8*)&Rt[bc][kb];
      acc = __builtin_amdgcn_mfma_f32_16x16x32_bf16(af, bf, acc, 0, 0, 0);
    }
    if (dcol < 24) {
      #pragma unroll
      for (int i = 0; i < 4; ++i) rp[drow + i][dcol] = acc[i];
    }
    __syncthreads();

    {  // gates + state update, one (batch,unit) per thread
      const float* xpb = xp + ((size_t)gb * NS + t) * N3 + u0 + ou;
      const float xz = xpb[0], xr = xpb[512], xh = xpb[1024];
      const float rz = rp[ob][ou]      + brec[ou];
      const float rr = rp[ob][8 + ou]  + brec[8 + ou];
      const float rh = rp[ob][16 + ou] + brec[16 + ou];
      const float z = 1.f / (1.f + __expf(-(xz + rz)));
      const float r = 1.f / (1.f + __expf(-(xr + rr)));
      const float e = __expf(2.f * (xh + r * rh));
      const float hh = (e - 1.f) / (e + 1.f);     // tanh
      hreg = z * hreg + (1.f - z) * hh;
      out[((size_t)gb * NS + t) * NU + u0 + ou] = hreg;
      if (t == NS - 1)
        out[(size_t)NB * NS * NU + (size_t)gb * NU + u0 + ou] = hreg;
      hx[((size_t)(t + 1) * NB + gb) * NU + u0 + ou] = f2bf(hreg);
    }
    __syncthreads();  // drains all stores (vmcnt 0) before signaling
    if (tid == 0) {
      __hip_atomic_fetch_add(&flags[(g << 7) + t], 1u, __ATOMIC_RELEASE,
                             __HIP_MEMORY_SCOPE_AGENT);
    }
  }
}

extern "C" void kernel_launch(void* const* d_in, const int* in_sizes, int n_in,
                              void* d_out, int out_size, void* d_ws, size_t ws_size,
                              hipStream_t stream) {
  const int*   x      = (const int*)d_in[0];
  const float* hidden = (const float*)d_in[1];
  const float* emb    = (const float*)d_in[2];
  const float* W      = (const float*)d_in[3];
  const float* R      = (const float*)d_in[4];
  const float* bias   = (const float*)d_in[5];
  float* out = (float*)d_out;

  char* ws = (char*)d_ws;
  float*          xp    = (float*)ws;                          // 50,331,648 B
  unsigned short* hx    = (unsigned short*)(ws + 50331648);    //  8,454,144 B
  unsigned int*   flags = (unsigned int*)(ws + 50331648 + 8454144);

  init_kernel<<<NB, NU, 0, stream>>>(hidden, hx, flags);
  dim3 gA(N3 / 64, (NB * NS) / 64);
  xproj_kernel<<<gA, 256, 0, stream>>>(x, emb, W, bias, xp);
  gru_scan_kernel<<<256, 128, 0, stream>>>(xp, hidden, R, bias, out, hx, flags);
}

// Round 2
// 1150.131 us; speedup vs baseline: 1.2646x; 1.2646x over previous
//
#include <hip/hip_runtime.h>
#include <hip/hip_bf16.h>

#define NB   64     // batch
#define NS   128    // seq len
#define ND   256    // embed dim
#define NU   512    // hidden units
#define N3   1536   // 3*NU

typedef __attribute__((ext_vector_type(4))) float  f32x4;
typedef __attribute__((ext_vector_type(8))) short  s16x8;

__device__ __forceinline__ unsigned short f2bf(float v) {
  unsigned u = __builtin_bit_cast(unsigned, v);
  u += 0x7fffu + ((u >> 16) & 1u);          // round-to-nearest-even
  return (unsigned short)(u >> 16);
}

// -------- init: hx[0] = bf16(hidden); zero sync flags (graph-replay safe) ------
__global__ void init_kernel(const float* __restrict__ hidden,
                            unsigned short* __restrict__ hx,
                            unsigned int* __restrict__ flags) {
  const int b = blockIdx.x, u = threadIdx.x;   // 64 x 512
  hx[b * NU + u] = f2bf(hidden[b * NU + u]);
  if (u < 128) flags[b * 128 + u] = 0u;        // 4 grp * 128 steps * 16 producers
}

// -------- phase 1: xp = gather(emb,x) @ W + b_in  (f32 SIMT, unchanged) --------
__global__ __launch_bounds__(256) void xproj_kernel(
    const int* __restrict__ x, const float* __restrict__ emb,
    const float* __restrict__ W, const float* __restrict__ bias,
    float* __restrict__ xp) {
  __shared__ float As[32][68];
  __shared__ float Bs[32][68];
  __shared__ int tok[64];
  const int tid = threadIdx.x;
  const int m0 = blockIdx.y * 64;
  const int n0 = blockIdx.x * 64;
  if (tid < 64) tok[tid] = x[m0 + tid];
  __syncthreads();
  const int tx = tid & 15, ty = tid >> 4;
  float acc[4][4] = {};
  for (int k0 = 0; k0 < ND; k0 += 32) {
    {
      const int m = tid & 63, kq = tid >> 6;
      const float* src = emb + (size_t)tok[m] * ND + k0 + kq * 8;
      const float4 v0 = *(const float4*)(src);
      const float4 v1 = *(const float4*)(src + 4);
      As[kq*8+0][m] = v0.x; As[kq*8+1][m] = v0.y;
      As[kq*8+2][m] = v0.z; As[kq*8+3][m] = v0.w;
      As[kq*8+4][m] = v1.x; As[kq*8+5][m] = v1.y;
      As[kq*8+6][m] = v1.z; As[kq*8+7][m] = v1.w;
    }
    {
      const int n = (tid & 15) * 4, k = tid >> 4;
      *(float4*)&Bs[k][n]    = *(const float4*)&W[(size_t)(k0 + k) * N3 + n0 + n];
      *(float4*)&Bs[k+16][n] = *(const float4*)&W[(size_t)(k0 + k + 16) * N3 + n0 + n];
    }
    __syncthreads();
    #pragma unroll
    for (int kk = 0; kk < 32; ++kk) {
      const float4 b4 = *(const float4*)&Bs[kk][tx * 4];
      float a[4];
      #pragma unroll
      for (int i = 0; i < 4; ++i) a[i] = As[kk][ty * 4 + i];
      #pragma unroll
      for (int i = 0; i < 4; ++i) {
        acc[i][0] += a[i] * b4.x;
        acc[i][1] += a[i] * b4.y;
        acc[i][2] += a[i] * b4.z;
        acc[i][3] += a[i] * b4.w;
      }
    }
    __syncthreads();
  }
  #pragma unroll
  for (int i = 0; i < 4; ++i) {
    const size_t row = (size_t)(m0 + ty * 4 + i) * N3 + n0 + tx * 4;
    float4 o;
    o.x = acc[i][0] + bias[n0 + tx*4 + 0];
    o.y = acc[i][1] + bias[n0 + tx*4 + 1];
    o.z = acc[i][2] + bias[n0 + tx*4 + 2];
    o.w = acc[i][3] + bias[n0 + tx*4 + 3];
    *(float4*)&xp[row] = o;
  }
}

// -------- phase 2: persistent GRU scan ----------------------------------------
// 64 blocks = 4 batch-groups (16 batches) x 16 unit-blocks (32 units -> 96 R cols).
// R slice resident in LDS for all 128 steps. Per step: poll 16 per-producer flags
// (relaxed) -> acquire fence -> stage h[t] via cache-bypassing atomic loads ->
// MFMA -> f32 gates -> h[t+1] via write-through atomic stores -> release-store
// own flag. No contended RMW, no per-poll cache maintenance.
__global__ __launch_bounds__(128) void gru_scan_kernel(
    const float* __restrict__ xp, const float* __restrict__ hidden,
    const float* __restrict__ R, const float* __restrict__ bias,
    float* __restrict__ out, unsigned short* __restrict__ hx,
    unsigned int* __restrict__ flags) {
  __shared__ unsigned short Rt[96][520];  // [col][k] bf16 (col = gate*32 + unit)
  __shared__ unsigned short hl[16][520];  // h[t] staged (16 batches x 512)
  __shared__ float rp[16][100];
  __shared__ float brec[96];

  const int bid = blockIdx.x;
  const int g   = bid >> 4;          // batch group 0..3
  const int p   = bid & 15;          // producer id within group
  const int u0  = p * 32;            // unit base
  const int tid = threadIdx.x;
  const int lane = tid & 63;
  const int wv   = tid >> 6;         // 2 waves

  // one-time: stage R columns transposed to bf16 ([col][k], k contiguous)
  for (int idx = tid; idx < 512 * 128; idx += 128) {
    const int k = idx >> 7, c = idx & 127;
    if (c < 96)
      Rt[c][k] = f2bf(R[(size_t)k * N3 + ((c >> 5) << 9) + u0 + (c & 31)]);
  }
  if (tid < 96) brec[tid] = bias[N3 + ((tid >> 5) << 9) + u0 + (tid & 31)];

  const int ob  = tid >> 3;          // batch within group 0..15
  const int uu4 = (tid & 7) << 2;    // 4 units per thread
  const int gb  = (g << 4) + ob;     // global batch
  float hr[4];
  {
    const float4 h0 = *(const float4*)&hidden[(size_t)gb * NU + u0 + uu4];
    hr[0] = h0.x; hr[1] = h0.y; hr[2] = h0.z; hr[3] = h0.w;
  }
  __syncthreads();

  const int ar = lane & 15;          // A frag row (batch)
  const int kg = lane >> 4;          // k-group
  const int cb = wv * 48 + (lane & 15);   // first B col for this lane
  const int drow = (lane >> 4) << 2;

  for (int t = 0; t < NS; ++t) {
    if (t > 0) {
      if (tid < 16) {
        unsigned int* f = &flags[(((g << 7) | (t - 1)) << 4) + tid];
        while (__hip_atomic_load(f, __ATOMIC_RELAXED,
                                 __HIP_MEMORY_SCOPE_AGENT) == 0u) {}
      }
      __builtin_amdgcn_fence(__ATOMIC_ACQUIRE, "agent");
      __syncthreads();
    }

    // prefetch this step's xp into registers (independent of h)
    const float* xpb = xp + ((size_t)gb * NS + t) * N3 + u0 + uu4;
    const float4 xzv = *(const float4*)(xpb);
    const float4 xrv = *(const float4*)(xpb + 512);
    const float4 xhv = *(const float4*)(xpb + 1024);

    {  // stage h[t]: 16 x 512 bf16 = 16 KB via cache-bypassing 8B atomic loads
      unsigned long long* hsrc =
          (unsigned long long*)(hx + ((size_t)t * NB + (g << 4)) * NU);
      #pragma unroll
      for (int i = 0; i < 16; ++i) {
        const int idx = i * 128 + tid;          // 0..2047 u64
        const unsigned long long v = __hip_atomic_load(
            &hsrc[idx], __ATOMIC_RELAXED, __HIP_MEMORY_SCOPE_AGENT);
        *(unsigned long long*)&hl[idx >> 7][(idx & 127) << 2] = v;
      }
    }
    __syncthreads();

    // rp[16][96] = h[16x512] @ Rslice[512x96], 3 col-tiles per wave
    f32x4 acc0 = {0.f,0.f,0.f,0.f}, acc1 = acc0, acc2 = acc0;
    #pragma unroll
    for (int ks = 0; ks < 16; ++ks) {
      const int kb = ks * 32 + kg * 8;
      const s16x8 af = *(const s16x8*)&hl[ar][kb];
      acc0 = __builtin_amdgcn_mfma_f32_16x16x32_bf16(
          af, *(const s16x8*)&Rt[cb][kb],      acc0, 0, 0, 0);
      acc1 = __builtin_amdgcn_mfma_f32_16x16x32_bf16(
          af, *(const s16x8*)&Rt[cb + 16][kb], acc1, 0, 0, 0);
      acc2 = __builtin_amdgcn_mfma_f32_16x16x32_bf16(
          af, *(const s16x8*)&Rt[cb + 32][kb], acc2, 0, 0, 0);
    }
    #pragma unroll
    for (int i = 0; i < 4; ++i) {
      rp[drow + i][cb]      = acc0[i];
      rp[drow + i][cb + 16] = acc1[i];
      rp[drow + i][cb + 32] = acc2[i];
    }
    __syncthreads();

    {  // gates + state update: 4 units per thread, all f32
      const float4 rzv = *(const float4*)&rp[ob][uu4];
      const float4 rrv = *(const float4*)&rp[ob][32 + uu4];
      const float4 rhv = *(const float4*)&rp[ob][64 + uu4];
      const float4 bz  = *(const float4*)&brec[uu4];
      const float4 br  = *(const float4*)&brec[32 + uu4];
      const float4 bh  = *(const float4*)&brec[64 + uu4];
      float xz[4] = {xzv.x, xzv.y, xzv.z, xzv.w};
      float xr[4] = {xrv.x, xrv.y, xrv.z, xrv.w};
      float xh[4] = {xhv.x, xhv.y, xhv.z, xhv.w};
      float rz[4] = {rzv.x + bz.x, rzv.y + bz.y, rzv.z + bz.z, rzv.w + bz.w};
      float rr[4] = {rrv.x + br.x, rrv.y + br.y, rrv.z + br.z, rrv.w + br.w};
      float rh[4] = {rhv.x + bh.x, rhv.y + bh.y, rhv.z + bh.z, rhv.w + bh.w};
      float4 ov;
      float* o = &ov.x;
      #pragma unroll
      for (int j = 0; j < 4; ++j) {
        const float z = 1.f / (1.f + __expf(-(xz[j] + rz[j])));
        const float r = 1.f / (1.f + __expf(-(xr[j] + rr[j])));
        const float e = __expf(2.f * (xh[j] + r * rh[j]));
        const float hh = (e - 1.f) / (e + 1.f);     // tanh
        hr[j] = z * hr[j] + (1.f - z) * hh;
        o[j] = hr[j];
      }
      *(float4*)&out[((size_t)gb * NS + t) * NU + u0 + uu4] = ov;
      if (t == NS - 1)
        *(float4*)&out[(size_t)NB * NS * NU + (size_t)gb * NU + u0 + uu4] = ov;
      const unsigned long long pk =
          (unsigned long long)f2bf(hr[0])        |
          ((unsigned long long)f2bf(hr[1]) << 16)|
          ((unsigned long long)f2bf(hr[2]) << 32)|
          ((unsigned long long)f2bf(hr[3]) << 48);
      __hip_atomic_store(
          (unsigned long long*)&hx[((size_t)(t + 1) * NB + gb) * NU + u0 + uu4],
          pk, __ATOMIC_RELAXED, __HIP_MEMORY_SCOPE_AGENT);
    }
    __syncthreads();   // drains every thread's stores (vmcnt 0) before signal
    if (tid == 0)
      __hip_atomic_store(&flags[(((g << 7) | t) << 4) + p], 1u,
                         __ATOMIC_RELEASE, __HIP_MEMORY_SCOPE_AGENT);
  }
}

extern "C" void kernel_launch(void* const* d_in, const int* in_sizes, int n_in,
                              void* d_out, int out_size, void* d_ws, size_t ws_size,
                              hipStream_t stream) {
  const int*   x      = (const int*)d_in[0];
  const float* hidden = (const float*)d_in[1];
  const float* emb    = (const float*)d_in[2];
  const float* W      = (const float*)d_in[3];
  const float* R      = (const float*)d_in[4];
  const float* bias   = (const float*)d_in[5];
  float* out = (float*)d_out;

  char* ws = (char*)d_ws;
  float*          xp    = (float*)ws;                          // 50,331,648 B
  unsigned short* hx    = (unsigned short*)(ws + 50331648);    //  8,454,144 B
  unsigned int*   flags = (unsigned int*)(ws + 50331648 + 8454144); // 32 KB

  init_kernel<<<NB, NU, 0, stream>>>(hidden, hx, flags);
  dim3 gA(N3 / 64, (NB * NS) / 64);
  xproj_kernel<<<gA, 256, 0, stream>>>(x, emb, W, bias, xp);
  gru_scan_kernel<<<64, 128, 0, stream>>>(xp, hidden, R, bias, out, hx, flags);
}

// Round 3
// 1014.883 us; speedup vs baseline: 1.4331x; 1.1333x over previous
//
#include <hip/hip_runtime.h>
#include <hip/hip_bf16.h>

#define NB   64     // batch
#define NS   128    // seq len
#define ND   256    // embed dim
#define NU   512    // hidden units
#define N3   1536   // 3*NU

typedef __attribute__((ext_vector_type(4))) float  f32x4;
typedef __attribute__((ext_vector_type(8))) short  s16x8;

__device__ __forceinline__ unsigned short f2bf(float v) {
  unsigned u = __builtin_bit_cast(unsigned, v);
  u += 0x7fffu + ((u >> 16) & 1u);          // round-to-nearest-even
  return (unsigned short)(u >> 16);
}

// -------- init: hx[0] = bf16(hidden); zero sync flags (graph-replay safe) ------
__global__ void init_kernel(const float* __restrict__ hidden,
                            unsigned short* __restrict__ hx,
                            unsigned int* __restrict__ flags) {
  const int b = blockIdx.x, u = threadIdx.x;   // 64 x 512
  hx[b * NU + u] = f2bf(hidden[b * NU + u]);
  if (u < 128) flags[b * 128 + u] = 0u;        // 4 grp * 128 steps * 16 producers
}

// -------- phase 1: xp = gather(emb,x) @ W + b_in  (f32 SIMT, unchanged) --------
__global__ __launch_bounds__(256) void xproj_kernel(
    const int* __restrict__ x, const float* __restrict__ emb,
    const float* __restrict__ W, const float* __restrict__ bias,
    float* __restrict__ xp) {
  __shared__ float As[32][68];
  __shared__ float Bs[32][68];
  __shared__ int tok[64];
  const int tid = threadIdx.x;
  const int m0 = blockIdx.y * 64;
  const int n0 = blockIdx.x * 64;
  if (tid < 64) tok[tid] = x[m0 + tid];
  __syncthreads();
  const int tx = tid & 15, ty = tid >> 4;
  float acc[4][4] = {};
  for (int k0 = 0; k0 < ND; k0 += 32) {
    {
      const int m = tid & 63, kq = tid >> 6;
      const float* src = emb + (size_t)tok[m] * ND + k0 + kq * 8;
      const float4 v0 = *(const float4*)(src);
      const float4 v1 = *(const float4*)(src + 4);
      As[kq*8+0][m] = v0.x; As[kq*8+1][m] = v0.y;
      As[kq*8+2][m] = v0.z; As[kq*8+3][m] = v0.w;
      As[kq*8+4][m] = v1.x; As[kq*8+5][m] = v1.y;
      As[kq*8+6][m] = v1.z; As[kq*8+7][m] = v1.w;
    }
    {
      const int n = (tid & 15) * 4, k = tid >> 4;
      *(float4*)&Bs[k][n]    = *(const float4*)&W[(size_t)(k0 + k) * N3 + n0 + n];
      *(float4*)&Bs[k+16][n] = *(const float4*)&W[(size_t)(k0 + k + 16) * N3 + n0 + n];
    }
    __syncthreads();
    #pragma unroll
    for (int kk = 0; kk < 32; ++kk) {
      const float4 b4 = *(const float4*)&Bs[kk][tx * 4];
      float a[4];
      #pragma unroll
      for (int i = 0; i < 4; ++i) a[i] = As[kk][ty * 4 + i];
      #pragma unroll
      for (int i = 0; i < 4; ++i) {
        acc[i][0] += a[i] * b4.x;
        acc[i][1] += a[i] * b4.y;
        acc[i][2] += a[i] * b4.z;
        acc[i][3] += a[i] * b4.w;
      }
    }
    __syncthreads();
  }
  #pragma unroll
  for (int i = 0; i < 4; ++i) {
    const size_t row = (size_t)(m0 + ty * 4 + i) * N3 + n0 + tx * 4;
    float4 o;
    o.x = acc[i][0] + bias[n0 + tx*4 + 0];
    o.y = acc[i][1] + bias[n0 + tx*4 + 1];
    o.z = acc[i][2] + bias[n0 + tx*4 + 2];
    o.w = acc[i][3] + bias[n0 + tx*4 + 3];
    *(float4*)&xp[row] = o;
  }
}

// -------- phase 2: persistent GRU scan ----------------------------------------
// 64 blocks = 4 batch-groups (16 batches) x 16 unit-blocks (32 units -> 96 R cols).
// All cross-block data (hx, flags) moves via agent-scope relaxed atomics, which
// bypass L2 and are served by the coherence point (LLC). Therefore NO cache
// maintenance ops (no buffer_wbl2 / buffer_inv) are needed:
//   release: __syncthreads() drains vmcnt (sc1 stores acked at LLC) -> relaxed
//            flag store afterwards is ordered at the LLC.
//   acquire: consumers' hx loads are sc1 (always fresh) and issue only after
//            the barrier that follows flag observation.
__global__ __launch_bounds__(128) void gru_scan_kernel(
    const float* __restrict__ xp, const float* __restrict__ hidden,
    const float* __restrict__ R, const float* __restrict__ bias,
    float* __restrict__ out, unsigned short* __restrict__ hx,
    unsigned int* __restrict__ flags) {
  __shared__ unsigned short Rt[96][520];  // [col][k] bf16 (col = gate*32 + unit)
  __shared__ unsigned short hl[16][520];  // h[t] staged (16 batches x 512)
  __shared__ float rp[16][100];
  __shared__ float brec[96];

  const int bid = blockIdx.x;
  const int g   = bid >> 4;          // batch group 0..3
  const int p   = bid & 15;          // producer id within group
  const int u0  = p * 32;            // unit base
  const int tid = threadIdx.x;
  const int lane = tid & 63;
  const int wv   = tid >> 6;         // 2 waves

  // one-time: stage R columns transposed to bf16 ([col][k], k contiguous)
  for (int idx = tid; idx < 512 * 128; idx += 128) {
    const int k = idx >> 7, c = idx & 127;
    if (c < 96)
      Rt[c][k] = f2bf(R[(size_t)k * N3 + ((c >> 5) << 9) + u0 + (c & 31)]);
  }
  if (tid < 96) brec[tid] = bias[N3 + ((tid >> 5) << 9) + u0 + (tid & 31)];

  const int ob  = tid >> 3;          // batch within group 0..15
  const int uu4 = (tid & 7) << 2;    // 4 units per thread
  const int gb  = (g << 4) + ob;     // global batch
  float hr[4];
  {
    const float4 h0 = *(const float4*)&hidden[(size_t)gb * NU + u0 + uu4];
    hr[0] = h0.x; hr[1] = h0.y; hr[2] = h0.z; hr[3] = h0.w;
  }
  __syncthreads();

  const int ar = lane & 15;          // A frag row (batch)
  const int kg = lane >> 4;          // k-group
  const int cb = wv * 48 + (lane & 15);   // first B col for this lane
  const int drow = (lane >> 4) << 2;

  for (int t = 0; t < NS; ++t) {
    // prefetch this step's xp into registers (independent of flags/h)
    const float* xpb = xp + ((size_t)gb * NS + t) * N3 + u0 + uu4;
    const float4 xzv = *(const float4*)(xpb);
    const float4 xrv = *(const float4*)(xpb + 512);
    const float4 xhv = *(const float4*)(xpb + 1024);

    if (t > 0) {
      if (tid < 16) {
        unsigned int* f = &flags[(((g << 7) | (t - 1)) << 4) + tid];
        while (__hip_atomic_load(f, __ATOMIC_RELAXED,
                                 __HIP_MEMORY_SCOPE_AGENT) == 0u) {}
      }
      asm volatile("" ::: "memory");   // no buffer_inv: hx loads are sc1/LLC
      __syncthreads();
    }

    {  // stage h[t]: 16 x 512 bf16 = 16 KB via L2-bypassing 8B atomic loads
      unsigned long long* hsrc =
          (unsigned long long*)(hx + ((size_t)t * NB + (g << 4)) * NU);
      #pragma unroll
      for (int i = 0; i < 16; ++i) {
        const int idx = i * 128 + tid;          // 0..2047 u64
        const unsigned long long v = __hip_atomic_load(
            &hsrc[idx], __ATOMIC_RELAXED, __HIP_MEMORY_SCOPE_AGENT);
        *(unsigned long long*)&hl[idx >> 7][(idx & 127) << 2] = v;
      }
    }
    __syncthreads();

    // rp[16][96] = h[16x512] @ Rslice[512x96], 3 col-tiles per wave
    f32x4 acc0 = {0.f,0.f,0.f,0.f}, acc1 = acc0, acc2 = acc0;
    #pragma unroll
    for (int ks = 0; ks < 16; ++ks) {
      const int kb = ks * 32 + kg * 8;
      const s16x8 af = *(const s16x8*)&hl[ar][kb];
      acc0 = __builtin_amdgcn_mfma_f32_16x16x32_bf16(
          af, *(const s16x8*)&Rt[cb][kb],      acc0, 0, 0, 0);
      acc1 = __builtin_amdgcn_mfma_f32_16x16x32_bf16(
          af, *(const s16x8*)&Rt[cb + 16][kb], acc1, 0, 0, 0);
      acc2 = __builtin_amdgcn_mfma_f32_16x16x32_bf16(
          af, *(const s16x8*)&Rt[cb + 32][kb], acc2, 0, 0, 0);
    }
    #pragma unroll
    for (int i = 0; i < 4; ++i) {
      rp[drow + i][cb]      = acc0[i];
      rp[drow + i][cb + 16] = acc1[i];
      rp[drow + i][cb + 32] = acc2[i];
    }
    __syncthreads();

    {  // gates + state update: 4 units per thread, all f32
      const float4 rzv = *(const float4*)&rp[ob][uu4];
      const float4 rrv = *(const float4*)&rp[ob][32 + uu4];
      const float4 rhv = *(const float4*)&rp[ob][64 + uu4];
      const float4 bz  = *(const float4*)&brec[uu4];
      const float4 br  = *(const float4*)&brec[32 + uu4];
      const float4 bh  = *(const float4*)&brec[64 + uu4];
      float xz[4] = {xzv.x, xzv.y, xzv.z, xzv.w};
      float xr[4] = {xrv.x, xrv.y, xrv.z, xrv.w};
      float xh[4] = {xhv.x, xhv.y, xhv.z, xhv.w};
      float rz[4] = {rzv.x + bz.x, rzv.y + bz.y, rzv.z + bz.z, rzv.w + bz.w};
      float rr[4] = {rrv.x + br.x, rrv.y + br.y, rrv.z + br.z, rrv.w + br.w};
      float rh[4] = {rhv.x + bh.x, rhv.y + bh.y, rhv.z + bh.z, rhv.w + bh.w};
      float4 ov;
      float* o = &ov.x;
      #pragma unroll
      for (int j = 0; j < 4; ++j) {
        const float z = 1.f / (1.f + __expf(-(xz[j] + rz[j])));
        const float r = 1.f / (1.f + __expf(-(xr[j] + rr[j])));
        const float e = __expf(2.f * (xh[j] + r * rh[j]));
        const float hh = (e - 1.f) / (e + 1.f);     // tanh
        hr[j] = z * hr[j] + (1.f - z) * hh;
        o[j] = hr[j];
      }
      *(float4*)&out[((size_t)gb * NS + t) * NU + u0 + uu4] = ov;
      if (t == NS - 1)
        *(float4*)&out[(size_t)NB * NS * NU + (size_t)gb * NU + u0 + uu4] = ov;
      const unsigned long long pk =
          (unsigned long long)f2bf(hr[0])        |
          ((unsigned long long)f2bf(hr[1]) << 16)|
          ((unsigned long long)f2bf(hr[2]) << 32)|
          ((unsigned long long)f2bf(hr[3]) << 48);
      __hip_atomic_store(
          (unsigned long long*)&hx[((size_t)(t + 1) * NB + gb) * NU + u0 + uu4],
          pk, __ATOMIC_RELAXED, __HIP_MEMORY_SCOPE_AGENT);
    }
    __syncthreads();   // emits s_waitcnt vmcnt(0): sc1 h-stores acked at LLC
    asm volatile("" ::: "memory");
    if (tid == 0)      // relaxed: ordered behind h-stores by the vmcnt drain
      __hip_atomic_store(&flags[(((g << 7) | t) << 4) + p], 1u,
                         __ATOMIC_RELAXED, __HIP_MEMORY_SCOPE_AGENT);
  }
}

extern "C" void kernel_launch(void* const* d_in, const int* in_sizes, int n_in,
                              void* d_out, int out_size, void* d_ws, size_t ws_size,
                              hipStream_t stream) {
  const int*   x      = (const int*)d_in[0];
  const float* hidden = (const float*)d_in[1];
  const float* emb    = (const float*)d_in[2];
  const float* W      = (const float*)d_in[3];
  const float* R      = (const float*)d_in[4];
  const float* bias   = (const float*)d_in[5];
  float* out = (float*)d_out;

  char* ws = (char*)d_ws;
  float*          xp    = (float*)ws;                          // 50,331,648 B
  unsigned short* hx    = (unsigned short*)(ws + 50331648);    //  8,454,144 B
  unsigned int*   flags = (unsigned int*)(ws + 50331648 + 8454144); // 32 KB

  init_kernel<<<NB, NU, 0, stream>>>(hidden, hx, flags);
  dim3 gA(N3 / 64, (NB * NS) / 64);
  xproj_kernel<<<gA, 256, 0, stream>>>(x, emb, W, bias, xp);
  gru_scan_kernel<<<64, 128, 0, stream>>>(xp, hidden, R, bias, out, hx, flags);
}

// Round 4
// 759.476 us; speedup vs baseline: 1.9151x; 1.3363x over previous
//
#include <hip/hip_runtime.h>
#include <hip/hip_bf16.h>

#define NB   64     // batch
#define NS   128    // seq len
#define ND   256    // embed dim
#define NU   512    // hidden units
#define N3   1536   // 3*NU

typedef __attribute__((ext_vector_type(4))) float  f32x4;
typedef __attribute__((ext_vector_type(8))) short  s16x8;
typedef unsigned long long u64;
typedef unsigned int       u32;
typedef unsigned short     u16;

__device__ __forceinline__ u16 f2bf(float v) {
  unsigned u = __builtin_bit_cast(unsigned, v);
  u += 0x7fffu + ((u >> 16) & 1u);          // round-to-nearest-even
  return (u16)(u >> 16);
}

// -------- init: hx[0] = bf16(hidden); zero wave-flags (graph-replay safe) ------
__global__ void init_kernel(const float* __restrict__ hidden,
                            u16* __restrict__ hx,
                            u32* __restrict__ flags) {
  const int b = blockIdx.x, u = threadIdx.x;   // 64 x 512
  hx[b * NU + u] = f2bf(hidden[b * NU + u]);
  const int i = b * NU + u;
  if (i < 4 * NS * 16 * 2) flags[i] = 0u;      // 4 grp * 128 steps * 16 blk * 2 wv
}

// -------- phase 1: xp = gather(emb,x) @ W + b_in  (f32 SIMT, unchanged) --------
__global__ __launch_bounds__(256) void xproj_kernel(
    const int* __restrict__ x, const float* __restrict__ emb,
    const float* __restrict__ W, const float* __restrict__ bias,
    float* __restrict__ xp) {
  __shared__ float As[32][68];
  __shared__ float Bs[32][68];
  __shared__ int tok[64];
  const int tid = threadIdx.x;
  const int m0 = blockIdx.y * 64;
  const int n0 = blockIdx.x * 64;
  if (tid < 64) tok[tid] = x[m0 + tid];
  __syncthreads();
  const int tx = tid & 15, ty = tid >> 4;
  float acc[4][4] = {};
  for (int k0 = 0; k0 < ND; k0 += 32) {
    {
      const int m = tid & 63, kq = tid >> 6;
      const float* src = emb + (size_t)tok[m] * ND + k0 + kq * 8;
      const float4 v0 = *(const float4*)(src);
      const float4 v1 = *(const float4*)(src + 4);
      As[kq*8+0][m] = v0.x; As[kq*8+1][m] = v0.y;
      As[kq*8+2][m] = v0.z; As[kq*8+3][m] = v0.w;
      As[kq*8+4][m] = v1.x; As[kq*8+5][m] = v1.y;
      As[kq*8+6][m] = v1.z; As[kq*8+7][m] = v1.w;
    }
    {
      const int n = (tid & 15) * 4, k = tid >> 4;
      *(float4*)&Bs[k][n]    = *(const float4*)&W[(size_t)(k0 + k) * N3 + n0 + n];
      *(float4*)&Bs[k+16][n] = *(const float4*)&W[(size_t)(k0 + k + 16) * N3 + n0 + n];
    }
    __syncthreads();
    #pragma unroll
    for (int kk = 0; kk < 32; ++kk) {
      const float4 b4 = *(const float4*)&Bs[kk][tx * 4];
      float a[4];
      #pragma unroll
      for (int i = 0; i < 4; ++i) a[i] = As[kk][ty * 4 + i];
      #pragma unroll
      for (int i = 0; i < 4; ++i) {
        acc[i][0] += a[i] * b4.x;
        acc[i][1] += a[i] * b4.y;
        acc[i][2] += a[i] * b4.z;
        acc[i][3] += a[i] * b4.w;
      }
    }
    __syncthreads();
  }
  #pragma unroll
  for (int i = 0; i < 4; ++i) {
    const size_t row = (size_t)(m0 + ty * 4 + i) * N3 + n0 + tx * 4;
    float4 o;
    o.x = acc[i][0] + bias[n0 + tx*4 + 0];
    o.y = acc[i][1] + bias[n0 + tx*4 + 1];
    o.z = acc[i][2] + bias[n0 + tx*4 + 2];
    o.w = acc[i][3] + bias[n0 + tx*4 + 3];
    *(float4*)&xp[row] = o;
  }
}

// -------- phase 2: persistent GRU scan, barrier-free dataflow ------------------
// 64 blocks = 4 batch-groups (16 batches) x 16 unit-blocks (32 units). Each of
// the 2 waves owns 16 units end-to-end: all 3 gate columns for those units live
// in its 3 MFMA accumulators, so gates read accs directly (no rp LDS, no
// barriers). A-fragments load straight from hx (sc1 atomics) into registers.
// Per-wave flags: u64 poll covers both waves of a producer block. Signal path:
// 4 hx stores -> vmcnt(0) -> flag store; out[] f32 stores are AFTER the flag.
__global__ __launch_bounds__(128) void gru_scan_kernel(
    const float* __restrict__ xp, const float* __restrict__ hidden,
    const float* __restrict__ R, const float* __restrict__ bias,
    float* __restrict__ out, u16* __restrict__ hx,
    u32* __restrict__ flags32) {
  __shared__ u16 Rt[96][520];   // [c][k]: c = wv*48 + gate*16 + cu
  u64* flags = (u64*)flags32;

  const int bid = blockIdx.x;
  const int g   = bid >> 4;          // batch group 0..3
  const int p   = bid & 15;          // producer block id within group
  const int u0  = p * 32;            // unit base of this block
  const int tid = threadIdx.x;
  const int lane = tid & 63;
  const int wv   = tid >> 6;

  // one-time: stage R columns transposed to bf16, remapped per-wave
  for (int idx = tid; idx < 512 * 128; idx += 128) {
    const int k = idx >> 7, c = idx & 127;
    if (c < 96) {
      const int wc = c / 48, r = c % 48, j = r >> 4, cuu = r & 15;
      Rt[c][k] = f2bf(R[(size_t)k * N3 + (j << 9) + u0 + (wc << 4) + cuu]);
    }
  }
  __syncthreads();

  const int ar  = lane & 15;          // A row (batch within group)
  const int kg  = lane >> 4;          // k-group
  const int cu  = lane & 15;          // unit within wave slice
  const int myu = u0 + (wv << 4) + cu;   // my global unit
  const int drow = kg << 2;           // batch base for D rows
  const int cb  = wv * 48 + cu;       // Rt row base (gate tile j at cb + 16j)

  const float bz = bias[N3 + myu];
  const float br = bias[N3 + 512 + myu];
  const float bh = bias[N3 + 1024 + myu];

  float hr[4];
  #pragma unroll
  for (int i = 0; i < 4; ++i)
    hr[i] = hidden[(size_t)((g << 4) + drow + i) * NU + myu];

  for (int t = 0; t < NS; ++t) {
    // xp prefetch: 4 batches x 3 gates, my unit (issued before the poll)
    float xg0[4], xg1[4], xg2[4];
    #pragma unroll
    for (int i = 0; i < 4; ++i) {
      const float* q = xp + ((size_t)(((g << 4) + drow + i) * NS) + t) * N3 + myu;
      xg0[i] = q[0]; xg1[i] = q[512]; xg2[i] = q[1024];
    }

    if (t > 0) {   // 16-lane parallel poll of all 16 producer u64 flags
      u64* f = flags + (((size_t)g * NS + (t - 1)) << 4);
      const u64 kDone = 0x0000000100000001ull;
      int rdy = (lane >= 16) ? 1 : 0;
      while (!__all(rdy)) {
        if (!rdy)
          rdy = (__hip_atomic_load(&f[lane], __ATOMIC_RELAXED,
                                   __HIP_MEMORY_SCOPE_AGENT) == kDone) ? 1 : 0;
      }
      asm volatile("" ::: "memory");
    }

    // load all 16 A-slabs into registers (16 B per slab per lane, sc1)
    u64 alo[16], ahi[16];
    u64* hrow = (u64*)(hx + ((size_t)t * NB + (g << 4) + ar) * NU);
    #pragma unroll
    for (int ks = 0; ks < 16; ++ks) {
      const int qi = (ks << 3) + (kg << 1);
      alo[ks] = __hip_atomic_load(&hrow[qi],     __ATOMIC_RELAXED, __HIP_MEMORY_SCOPE_AGENT);
      ahi[ks] = __hip_atomic_load(&hrow[qi + 1], __ATOMIC_RELAXED, __HIP_MEMORY_SCOPE_AGENT);
    }

    // rp for my 16 units x 3 gates: 48 MFMAs, accumulators only
    f32x4 a0 = {0.f,0.f,0.f,0.f}, a1 = a0, a2 = a0;
    #pragma unroll
    for (int ks = 0; ks < 16; ++ks) {
      union { u64 q[2]; s16x8 v; } af;
      af.q[0] = alo[ks]; af.q[1] = ahi[ks];
      const int kb = (ks << 5) + (kg << 3);
      a0 = __builtin_amdgcn_mfma_f32_16x16x32_bf16(af.v, *(const s16x8*)&Rt[cb][kb],      a0, 0,0,0);
      a1 = __builtin_amdgcn_mfma_f32_16x16x32_bf16(af.v, *(const s16x8*)&Rt[cb + 16][kb], a1, 0,0,0);
      a2 = __builtin_amdgcn_mfma_f32_16x16x32_bf16(af.v, *(const s16x8*)&Rt[cb + 32][kb], a2, 0,0,0);
    }

    // gates straight from accumulators: D row = drow+i (batch), col = cu (unit)
    #pragma unroll
    for (int i = 0; i < 4; ++i) {
      const float z = 1.f / (1.f + __expf(-(xg0[i] + a0[i] + bz)));
      const float r = 1.f / (1.f + __expf(-(xg1[i] + a1[i] + br)));
      const float e = __expf(2.f * (xg2[i] + r * (a2[i] + bh)));
      const float hh = (e - 1.f) / (e + 1.f);     // tanh
      hr[i] = z * hr[i] + (1.f - z) * hh;
    }

    if (t < NS - 1) {   // signal path: hx stores -> vmcnt(0) -> own wave flag
      #pragma unroll
      for (int i = 0; i < 4; ++i)
        __hip_atomic_store(&hx[((size_t)(t + 1) * NB + (g << 4) + drow + i) * NU + myu],
                           f2bf(hr[i]), __ATOMIC_RELAXED, __HIP_MEMORY_SCOPE_AGENT);
      asm volatile("s_waitcnt vmcnt(0)" ::: "memory");
      if (lane == 0)
        __hip_atomic_store(&flags32[((((size_t)g * NS + t) << 4) + p) * 2 + wv], 1u,
                           __ATOMIC_RELAXED, __HIP_MEMORY_SCOPE_AGENT);
    }

    // out stores AFTER the flag (drained by next step's vmcnt(0))
    #pragma unroll
    for (int i = 0; i < 4; ++i)
      out[((size_t)((g << 4) + drow + i) * NS + t) * NU + myu] = hr[i];
    if (t == NS - 1) {
      #pragma unroll
      for (int i = 0; i < 4; ++i)
        out[(size_t)NB * NS * NU + (size_t)((g << 4) + drow + i) * NU + myu] = hr[i];
    }
  }
}

extern "C" void kernel_launch(void* const* d_in, const int* in_sizes, int n_in,
                              void* d_out, int out_size, void* d_ws, size_t ws_size,
                              hipStream_t stream) {
  const int*   x      = (const int*)d_in[0];
  const float* hidden = (const float*)d_in[1];
  const float* emb    = (const float*)d_in[2];
  const float* W      = (const float*)d_in[3];
  const float* R      = (const float*)d_in[4];
  const float* bias   = (const float*)d_in[5];
  float* out = (float*)d_out;

  char* ws = (char*)d_ws;
  float* xp    = (float*)ws;                            // 50,331,648 B
  u16*   hx    = (u16*)(ws + 50331648);                 //  8,388,608 B (128 slots)
  u32*   flags = (u32*)(ws + 50331648 + 8454144);       //     65,536 B

  init_kernel<<<NB, NU, 0, stream>>>(hidden, hx, flags);
  dim3 gA(N3 / 64, (NB * NS) / 64);
  xproj_kernel<<<gA, 256, 0, stream>>>(x, emb, W, bias, xp);
  gru_scan_kernel<<<64, 128, 0, stream>>>(xp, hidden, R, bias, out, hx, flags);
}